// Round 1
// baseline (262.471 us; speedup 1.0000x reference)
//
#include <hip/hip_runtime.h>

// Softmax over 32M fp32: out = exp(x) / sum(exp(x))  (no max-subtraction, per reference)
//
// Two-pass, memory-bound design:
//   Pass 1: grid-stride float4 loads, per-thread exp-sum, wave64 shuffle reduce,
//           LDS reduce across waves, one atomicAdd(float) per block into d_ws[0].
//   Pass 2: grid-stride float4 loads, recompute exp, multiply by 1/sum, float4 store.
// d_ws[0] is zeroed via hipMemsetAsync (graph-capturable) before pass 1.

#define BLOCK 256
#define GRID 2048  // 256 CUs x 8 blocks/CU

__global__ __launch_bounds__(BLOCK) void softmax_reduce(
    const float* __restrict__ inp, float* __restrict__ sum_out, int n4) {
  const float4* __restrict__ in4 = (const float4*)inp;
  int tid = blockIdx.x * BLOCK + threadIdx.x;
  int stride = gridDim.x * BLOCK;

  float s = 0.0f;
  for (int i = tid; i < n4; i += stride) {
    float4 v = in4[i];
    s += __expf(v.x) + __expf(v.y) + __expf(v.z) + __expf(v.w);
  }

  // wave64 butterfly reduce
  #pragma unroll
  for (int off = 32; off > 0; off >>= 1)
    s += __shfl_down(s, off, 64);

  __shared__ float wsum[BLOCK / 64];
  int wave = threadIdx.x >> 6;
  int lane = threadIdx.x & 63;
  if (lane == 0) wsum[wave] = s;
  __syncthreads();
  if (threadIdx.x == 0) {
    float t = 0.0f;
    #pragma unroll
    for (int w = 0; w < BLOCK / 64; ++w) t += wsum[w];
    atomicAdd(sum_out, t);  // device-scope by default on CDNA
  }
}

__global__ __launch_bounds__(BLOCK) void softmax_scale(
    const float* __restrict__ inp, float* __restrict__ out,
    const float* __restrict__ sum_ptr, int n4) {
  __shared__ float rinv_s;
  if (threadIdx.x == 0) rinv_s = 1.0f / (*sum_ptr);
  __syncthreads();
  float r = rinv_s;

  const float4* __restrict__ in4 = (const float4*)inp;
  float4* __restrict__ out4 = (float4*)out;
  int tid = blockIdx.x * BLOCK + threadIdx.x;
  int stride = gridDim.x * BLOCK;

  for (int i = tid; i < n4; i += stride) {
    float4 v = in4[i];
    float4 o;
    o.x = __expf(v.x) * r;
    o.y = __expf(v.y) * r;
    o.z = __expf(v.z) * r;
    o.w = __expf(v.w) * r;
    out4[i] = o;
  }
}

extern "C" void kernel_launch(void* const* d_in, const int* in_sizes, int n_in,
                              void* d_out, int out_size, void* d_ws, size_t ws_size,
                              hipStream_t stream) {
  const float* inp = (const float*)d_in[0];
  float* out = (float*)d_out;
  float* sum_ws = (float*)d_ws;
  int n = in_sizes[0];
  int n4 = n >> 2;  // N = 2^25, divisible by 4

  hipMemsetAsync(sum_ws, 0, sizeof(float), stream);
  softmax_reduce<<<GRID, BLOCK, 0, stream>>>(inp, sum_ws, n4);
  softmax_scale<<<GRID, BLOCK, 0, stream>>>(inp, out, sum_ws, n4);
}

// Round 3
// 247.610 us; speedup vs baseline: 1.0600x; 1.0600x over previous
//
#include <hip/hip_runtime.h>

// Softmax over 32M fp32: out = exp(x) / sum(exp(x))  (no max-subtraction, per reference)
//
// Two-pass, memory-bound:
//   Pass 1: grid-stride float4 loads, per-thread exp-sum, wave64 shuffle reduce,
//           LDS reduce, per-block partial sum -> d_ws[blockIdx] (no atomics, no init).
//   Pass 2: each block re-reduces the 2048 partials (8 KB, L2-hot), then grid-stride
//           float4 exp+scale with non-temporal stores (keep input resident in L3).

#define BLOCK 256
#define RGRID 2048  // 2048 blocks x 4 waves = 8192 waves = full residency
#define SGRID 2048

// clang-native vector type: __builtin_nontemporal_store requires it
// (HIP's float4 is a class and is rejected).
typedef float vfloat4 __attribute__((ext_vector_type(4)));

__global__ __launch_bounds__(BLOCK) void softmax_reduce(
    const float* __restrict__ inp, float* __restrict__ partials, int n4) {
  const vfloat4* __restrict__ in4 = (const vfloat4*)inp;
  int tid = blockIdx.x * BLOCK + threadIdx.x;
  int stride = gridDim.x * BLOCK;

  float s0 = 0.0f, s1 = 0.0f;
  int i = tid;
  // unroll x2 for ILP (two loads in flight)
  for (; i + stride < n4; i += 2 * stride) {
    vfloat4 a = in4[i];
    vfloat4 b = in4[i + stride];
    s0 += __expf(a.x) + __expf(a.y) + __expf(a.z) + __expf(a.w);
    s1 += __expf(b.x) + __expf(b.y) + __expf(b.z) + __expf(b.w);
  }
  for (; i < n4; i += stride) {
    vfloat4 a = in4[i];
    s0 += __expf(a.x) + __expf(a.y) + __expf(a.z) + __expf(a.w);
  }
  float s = s0 + s1;

  #pragma unroll
  for (int off = 32; off > 0; off >>= 1)
    s += __shfl_down(s, off, 64);

  __shared__ float wsum[BLOCK / 64];
  if ((threadIdx.x & 63) == 0) wsum[threadIdx.x >> 6] = s;
  __syncthreads();
  if (threadIdx.x == 0)
    partials[blockIdx.x] = wsum[0] + wsum[1] + wsum[2] + wsum[3];
}

__global__ __launch_bounds__(BLOCK) void softmax_scale(
    const float* __restrict__ inp, float* __restrict__ out,
    const float* __restrict__ partials, int n4) {
  // Every block independently reduces the RGRID partials (8 KB, L2-hot).
  float t = 0.0f;
  #pragma unroll
  for (int i = 0; i < RGRID / BLOCK; ++i)
    t += partials[i * BLOCK + threadIdx.x];

  #pragma unroll
  for (int off = 32; off > 0; off >>= 1)
    t += __shfl_down(t, off, 64);

  __shared__ float wsum[BLOCK / 64];
  if ((threadIdx.x & 63) == 0) wsum[threadIdx.x >> 6] = t;
  __syncthreads();
  float r = 1.0f / (wsum[0] + wsum[1] + wsum[2] + wsum[3]);

  const vfloat4* __restrict__ in4 = (const vfloat4*)inp;
  vfloat4* __restrict__ out4 = (vfloat4*)out;
  int tid = blockIdx.x * BLOCK + threadIdx.x;
  int stride = gridDim.x * BLOCK;

  int i = tid;
  for (; i + stride < n4; i += 2 * stride) {
    vfloat4 a = in4[i];
    vfloat4 b = in4[i + stride];
    vfloat4 oa, ob;
    oa.x = __expf(a.x) * r; oa.y = __expf(a.y) * r;
    oa.z = __expf(a.z) * r; oa.w = __expf(a.w) * r;
    ob.x = __expf(b.x) * r; ob.y = __expf(b.y) * r;
    ob.z = __expf(b.z) * r; ob.w = __expf(b.w) * r;
    __builtin_nontemporal_store(oa, &out4[i]);
    __builtin_nontemporal_store(ob, &out4[i + stride]);
  }
  for (; i < n4; i += stride) {
    vfloat4 a = in4[i];
    vfloat4 oa;
    oa.x = __expf(a.x) * r; oa.y = __expf(a.y) * r;
    oa.z = __expf(a.z) * r; oa.w = __expf(a.w) * r;
    __builtin_nontemporal_store(oa, &out4[i]);
  }
}

extern "C" void kernel_launch(void* const* d_in, const int* in_sizes, int n_in,
                              void* d_out, int out_size, void* d_ws, size_t ws_size,
                              hipStream_t stream) {
  const float* inp = (const float*)d_in[0];
  float* out = (float*)d_out;
  float* partials = (float*)d_ws;  // RGRID floats
  int n = in_sizes[0];
  int n4 = n >> 2;  // N = 2^25, divisible by 4

  softmax_reduce<<<RGRID, BLOCK, 0, stream>>>(inp, partials, n4);
  softmax_scale<<<SGRID, BLOCK, 0, stream>>>(inp, out, partials, n4);
}